// Round 10
// baseline (129.195 us; speedup 1.0000x reference)
//
#include <hip/hip_runtime.h>
#include <hip/hip_bf16.h>
#include <stdint.h>
#include <stddef.h>

#define DIM   2048
#define NEXP  64
#define NTOK  32768
#define KF    64                       // 2048/32 k-fragments (global)
#define OFF_IDX  (NTOK*NEXP)           // 2097152
#define OFF_TSC  (OFF_IDX + NTOK*2)    // 2162688
#define TAU   5e-4f

typedef __attribute__((ext_vector_type(8))) short  short8;
typedef __attribute__((ext_vector_type(4))) float  f32x4;

__device__ __forceinline__ unsigned short bf16_rne(float f) {
    unsigned u = __builtin_bit_cast(unsigned, f);
    u += 0x7fffu + ((u >> 16) & 1u);
    return (unsigned short)(u >> 16);
}
__device__ __forceinline__ float bf16_up(unsigned short s) {
    unsigned u = ((unsigned)s) << 16;
    return __builtin_bit_cast(float, u);
}

// ---------------------------------------------------------------------------
// Pre-kernel: split W into 2 bf16 terms (hi/mid) in MFMA B-fragment order.
// short idx = ((((term*KF+kf)*4+nf)*64)+lane)*8 + j  (262144 shorts = 512KB)
// Also zeroes the ambiguous-token counter (runs before router_mfma).
// ---------------------------------------------------------------------------
__global__ __launch_bounds__(256) void wsplit(const float* __restrict__ W,
                                              short* __restrict__ warr,
                                              int* __restrict__ cnt) {
    int idx  = blockIdx.x * 256 + threadIdx.x;   // 0..262143
    if (idx == 0) *cnt = 0;
    int j    = idx & 7;
    int lane = (idx >> 3) & 63;
    int nf   = (idx >> 9) & 3;
    int kf   = (idx >> 11) & 63;
    int term = idx >> 17;                        // 0..1
    int e = nf * 16 + (lane & 15);
    int d = kf * 32 + (lane >> 4) * 8 + j;
    float w = W[e * DIM + d];
    unsigned short h  = bf16_rne(w);
    float r1 = w - bf16_up(h);
    unsigned short md = bf16_rne(r1);
    warr[idx] = (short)((term == 0) ? h : md);
}

__device__ __forceinline__ bool gtie(float a, int ia, float b, int ib) {
    return (a > b) || (a == b && ia < ib);
}

// ---------------------------------------------------------------------------
// Kernel A (R10): split-K x2. Wave = 16 tokens x 64 experts x 1024 dims
// (kh = K-half). 4096 waves = 4/SIMD (launch_bounds caps VGPR at 128).
// A-ring 2-deep, B 1-ahead dbuf. K-halves merged via LDS; kh=0 waves run
// the R8-verified epilogue (softmax write, top-3, TAU-flagging).
// ---------------------------------------------------------------------------
__global__ __launch_bounds__(256, 4) void router_mfma(
        const float* __restrict__ X, const short* __restrict__ Wsp,
        const float* __restrict__ bias, float* __restrict__ out,
        int* __restrict__ cnt, int* __restrict__ list) {
    __shared__ f32x4 part[2][4][64];           // [tokgrp][nf][lane], 8 KB
    const int lane = threadIdx.x & 63;
    const int wid  = threadIdx.x >> 6;         // 0..3
    const int tg   = wid >> 1;                 // token group in block
    const int kh   = wid & 1;                  // K-half
    const int tok0 = (blockIdx.x * 2 + tg) * 16;
    const int l15  = lane & 15;
    const int l4   = lane >> 4;
    const int kf0  = kh * 32;                  // global kf offset

    const float* xr = X + (size_t)(tok0 + l15) * DIM + kh * 1024 + l4 * 8;
    const short8* wp = (const short8*)Wsp + lane;  // + ((t*KF+kf)*4+n)*64

    f32x4 acc[4];
#pragma unroll
    for (int n = 0; n < 4; n++) acc[n] = (f32x4)0.0f;

    // 2-deep A prefetch ring (static idx via 2-phase unroll), 1-ahead B dbuf
    f32x4  a_pf[2][2];
    short8 b_pf[2][2][4];
#pragma unroll
    for (int p = 0; p < 2; p++) {
        a_pf[p][0] = *(const f32x4*)(xr + p * 32);
        a_pf[p][1] = *(const f32x4*)(xr + p * 32 + 4);
    }
#pragma unroll
    for (int t = 0; t < 2; t++)
#pragma unroll
        for (int n = 0; n < 4; n++)
            b_pf[0][t][n] = wp[((t * KF + kf0) * 4 + n) * 64];

#pragma unroll 1
    for (int base = 0; base < 32; base += 2) {
#pragma unroll
        for (int p = 0; p < 2; ++p) {
            const int kf  = base + p;                      // local 0..31
            const int kn1 = (kf + 1 < 32) ? kf + 1 : 31;
            const int kn2 = (kf + 2 < 32) ? kf + 2 : 31;

            // B prefetch for kf+1 into the other buffer
#pragma unroll
            for (int t = 0; t < 2; t++)
#pragma unroll
                for (int n = 0; n < 4; n++)
                    b_pf[(p + 1) & 1][t][n] = wp[((t * KF + kf0 + kn1) * 4 + n) * 64];

            // take current A, reissue its ring slot for kf+2
            f32x4 a0 = a_pf[p][0], a1 = a_pf[p][1];
            a_pf[p][0] = *(const f32x4*)(xr + kn2 * 32);
            a_pf[p][1] = *(const f32x4*)(xr + kn2 * 32 + 4);

            // 2-way bf16 split of A (8 elems)
            short8 ah, am;
#pragma unroll
            for (int j = 0; j < 8; j++) {
                float v = (j < 4) ? a0[j & 3] : a1[j & 3];
                unsigned short h  = bf16_rne(v);
                float r1 = v - bf16_up(h);
                unsigned short md = bf16_rne(r1);
                ah[j] = (short)h;
                am[j] = (short)md;
            }

#pragma unroll
            for (int n = 0; n < 4; n++) {
                f32x4 c = acc[n];
                c = __builtin_amdgcn_mfma_f32_16x16x32_bf16(ah, b_pf[p & 1][0][n], c, 0, 0, 0);
                c = __builtin_amdgcn_mfma_f32_16x16x32_bf16(ah, b_pf[p & 1][1][n], c, 0, 0, 0);
                c = __builtin_amdgcn_mfma_f32_16x16x32_bf16(am, b_pf[p & 1][0][n], c, 0, 0, 0);
                c = __builtin_amdgcn_mfma_f32_16x16x32_bf16(am, b_pf[p & 1][1][n], c, 0, 0, 0);
                acc[n] = c;
            }
        }
    }

    // ---------------- merge K-halves via LDS -------------------------------
    if (kh == 1) {
#pragma unroll
        for (int n = 0; n < 4; n++) part[tg][n][lane] = acc[n];
    }
    __syncthreads();
    if (kh == 1) return;
#pragma unroll
    for (int n = 0; n < 4; n++) acc[n] += part[tg][n][lane];

    // ------------- epilogue: bias + softmax + top-3 + flag (R8-verified) ---
    float bv[4];
#pragma unroll
    for (int n = 0; n < 4; n++) bv[n] = bias[n * 16 + l15];

#pragma unroll
    for (int r = 0; r < 4; r++) {
        const int t = tok0 + l4 * 4 + r;       // C row = (lane>>4)*4+reg
        float v[4];
#pragma unroll
        for (int n = 0; n < 4; n++) v[n] = acc[n][r] + bv[n];

        float mx = fmaxf(fmaxf(v[0], v[1]), fmaxf(v[2], v[3]));
#pragma unroll
        for (int s = 1; s < 16; s <<= 1) mx = fmaxf(mx, __shfl_xor(mx, s, 64));

        float p[4], den = 0.0f;
#pragma unroll
        for (int n = 0; n < 4; n++) { p[n] = __expf(v[n] - mx); den += p[n]; }
#pragma unroll
        for (int s = 1; s < 16; s <<= 1) den += __shfl_xor(den, s, 64);
        const float inv = 1.0f / den;
#pragma unroll
        for (int n = 0; n < 4; n++)
            out[(size_t)t * 64 + n * 16 + l15] = p[n] * inv;

        // local top-3 over this lane's 4 experts
        float v1 = -3.4e38f, v2 = -3.4e38f, v3 = -3.4e38f;
        int   i1 = 9999,     i2 = 9999,     i3 = 9999;
#pragma unroll
        for (int n = 0; n < 4; n++) {
            float vv = v[n]; int ii = n * 16 + l15;
            if (gtie(vv, ii, v1, i1))      { v3=v2;i3=i2; v2=v1;i2=i1; v1=vv;i1=ii; }
            else if (gtie(vv, ii, v2, i2)) { v3=v2;i3=i2; v2=vv;i2=ii; }
            else if (gtie(vv, ii, v3, i3)) { v3=vv;i3=ii; }
        }
        // butterfly merge across the token's 16 lanes
#pragma unroll
        for (int s = 1; s < 16; s <<= 1) {
            float ov1=__shfl_xor(v1,s,64), ov2=__shfl_xor(v2,s,64), ov3=__shfl_xor(v3,s,64);
            int   oi1=__shfl_xor(i1,s,64), oi2=__shfl_xor(i2,s,64), oi3=__shfl_xor(i3,s,64);
            bool a1 = gtie(v1,i1,ov1,oi1);
            float w1 = a1?v1:ov1;  int k1 = a1?i1:oi1;
            float x1 = a1?v2:ov2;  int xi1= a1?i2:oi2;   // winner's 2nd
            float x2 = a1?v3:ov3;  int xi2= a1?i3:oi3;   // winner's 3rd
            float y1 = a1?ov1:v1;  int yi1= a1?oi1:i1;   // loser's 1st
            float y2 = a1?ov2:v2;  int yi2= a1?oi2:i2;   // loser's 2nd
            bool a2 = gtie(x1,xi1,y1,yi1);
            float w2 = a2?x1:y1;   int k2 = a2?xi1:yi1;
            float w3; int k3;
            if (a2) { bool a3 = gtie(x2,xi2,y1,yi1); w3 = a3?x2:y1; k3 = a3?xi2:yi1; }
            else    { bool a3 = gtie(x1,xi1,y2,yi2); w3 = a3?x1:y2; k3 = a3?xi1:yi2; }
            v1=w1;i1=k1; v2=w2;i2=k2; v3=w3;i3=k3;
        }
        if (l15 == 0) {
            out[OFF_IDX + (size_t)t * 2 + 0] = (float)i1;
            out[OFF_IDX + (size_t)t * 2 + 1] = (float)i2;
            out[OFF_TSC + (size_t)t * 2 + 0] = __expf(v1 - mx) * inv;
            out[OFF_TSC + (size_t)t * 2 + 1] = __expf(v2 - mx) * inv;
            if ((v1 - v2 < TAU) || (v2 - v3 < TAU)) {
                int slot = atomicAdd(cnt, 1);
                list[slot] = t;
            }
        }
    }
}

// ---------------------------------------------------------------------------
// Kernel B: exact np-chain recompute for flagged tokens (R3-R9 verified
// arithmetic): logit[t][e] = sequential fmaf over d=0..2047 asc, then +b[e].
// ---------------------------------------------------------------------------
__global__ __launch_bounds__(256, 2) void router_exact(
        const float* __restrict__ X, const float* __restrict__ W,
        const float* __restrict__ Bb, float* __restrict__ out,
        const int* __restrict__ cnt, const int* __restrict__ list) {
    __shared__ float xrow[2048];
    __shared__ char  wbuf[2][64 * 272] __attribute__((aligned(16)));
    const int tid = threadIdx.x;
    const int n   = *cnt;

    for (int ii = blockIdx.x; ii < n; ii += gridDim.x) {
        const int t = list[ii];
#pragma unroll
        for (int q = 0; q < 2; ++q) {
            int s = tid + q * 256;               // 0..511 quads
            *(f32x4*)&xrow[s * 4] = *(const f32x4*)(X + (size_t)t * DIM + s * 4);
        }
#pragma unroll
        for (int q = 0; q < 4; ++q) {
            int s = tid + q * 256;               // 0..1023: e = s>>4, dq = s&15
            int e = s >> 4, dq = s & 15;
            f32x4 wv = *(const f32x4*)(W + (size_t)e * DIM + dq * 4);
            *(f32x4*)(wbuf[0] + e * 272 + ((16 * dq) ^ ((e & 7) << 4))) = wv;
        }
        __syncthreads();

        float acc = 0.0f;
#pragma unroll 1
        for (int c = 0; c < 32; ++c) {
            if (c + 1 < 32) {
#pragma unroll
                for (int q = 0; q < 4; ++q) {
                    int s = tid + q * 256;
                    int e = s >> 4, dq = s & 15;
                    f32x4 wv = *(const f32x4*)(W + (size_t)e * DIM + (c + 1) * 64 + dq * 4);
                    *(f32x4*)(wbuf[(c + 1) & 1] + e * 272 + ((16 * dq) ^ ((e & 7) << 4))) = wv;
                }
            }
            if (tid < 64) {
                const char* wb = wbuf[c & 1] + tid * 272;
                const int sw = (tid & 7) << 4;
#pragma unroll
                for (int dq = 0; dq < 16; ++dq) {
                    f32x4 xq = *(const f32x4*)&xrow[c * 64 + dq * 4];
                    f32x4 wv = *(const f32x4*)(wb + ((16 * dq) ^ sw));
#pragma unroll
                    for (int j = 0; j < 4; ++j)
                        acc = fmaf(xq[j], wv[j], acc);   // strict ascending d
                }
            }
            __syncthreads();
        }

        if (tid < 64) {
            const int lane = tid;
            const float lg = acc + Bb[lane];
            float m = lg;
#pragma unroll
            for (int s = 1; s < 64; s <<= 1) m = fmaxf(m, __shfl_xor(m, s, 64));
            const float p = __expf(lg - m);
            float den = p;
#pragma unroll
            for (int s = 1; s < 64; s <<= 1) den += __shfl_xor(den, s, 64);
            const float inv = 1.0f / den;
            out[(size_t)t * 64 + lane] = p * inv;

            float v1 = lg, v2 = -3.4e38f;
            int   i1 = lane, i2 = 127;
#pragma unroll
            for (int s = 1; s < 64; s <<= 1) {
                float ov1 = __shfl_xor(v1, s, 64), ov2 = __shfl_xor(v2, s, 64);
                int   oi1 = __shfl_xor(i1, s, 64), oi2 = __shfl_xor(i2, s, 64);
                bool  aw  = gtie(v1, i1, ov1, oi1);
                float nv1 = aw ? v1 : ov1;  int ni1 = aw ? i1 : oi1;
                float cv  = aw ? ov1 : v1;  int ci  = aw ? oi1 : i1;
                float sv  = aw ? v2 : ov2;  int si  = aw ? i2 : oi2;
                bool  c2  = gtie(cv, ci, sv, si);
                v1 = nv1; i1 = ni1;
                v2 = c2 ? cv : sv; i2 = c2 ? ci : si;
            }
            if (lane == 0) {
                out[OFF_IDX + (size_t)t * 2 + 0] = (float)i1;
                out[OFF_IDX + (size_t)t * 2 + 1] = (float)i2;
                out[OFF_TSC + (size_t)t * 2 + 0] = __expf(v1 - m) * inv;
                out[OFF_TSC + (size_t)t * 2 + 1] = __expf(v2 - m) * inv;
            }
        }
        __syncthreads();
    }
}

extern "C" void kernel_launch(void* const* d_in, const int* in_sizes, int n_in,
                              void* d_out, int out_size, void* d_ws, size_t ws_size,
                              hipStream_t stream) {
    const float* X = (const float*)d_in[0];   // [4,8192,2048] f32
    const float* W = (const float*)d_in[1];   // [64,2048] f32
    const float* b = (const float*)d_in[2];   // [64] f32
    float* out  = (float*)d_out;
    short* Wsp  = (short*)d_ws;                       // 512 KB
    int*   cnt  = (int*)((char*)d_ws + 524288);       // 4 B
    int*   list = (int*)((char*)d_ws + 524292);       // up to 128 KB

    wsplit<<<1024, 256, 0, stream>>>(W, Wsp, cnt);
    router_mfma<<<NTOK / 32, 256, 0, stream>>>(X, Wsp, b, out, cnt, list);
    router_exact<<<512, 256, 0, stream>>>(X, W, b, out, cnt, list);
}

// Round 11
// 127.850 us; speedup vs baseline: 1.0105x; 1.0105x over previous
//
#include <hip/hip_runtime.h>
#include <hip/hip_bf16.h>
#include <stdint.h>
#include <stddef.h>

#define DIM   2048
#define NEXP  64
#define NTOK  32768
#define KF    64                       // 2048/32 k-fragments (global)
#define OFF_IDX  (NTOK*NEXP)           // 2097152
#define OFF_TSC  (OFF_IDX + NTOK*2)    // 2162688
#define TAU   5e-4f

typedef __attribute__((ext_vector_type(8))) short  short8;
typedef __attribute__((ext_vector_type(4))) float  f32x4;

__device__ __forceinline__ unsigned short bf16_rne(float f) {
    unsigned u = __builtin_bit_cast(unsigned, f);
    u += 0x7fffu + ((u >> 16) & 1u);
    return (unsigned short)(u >> 16);
}
__device__ __forceinline__ float bf16_up(unsigned short s) {
    unsigned u = ((unsigned)s) << 16;
    return __builtin_bit_cast(float, u);
}

// ---------------------------------------------------------------------------
// Pre-kernel: split W into 2 bf16 terms (hi/mid) in MFMA B-fragment order.
// short idx = ((((term*KF+kf)*4+nf)*64)+lane)*8 + j  (262144 shorts = 512KB)
// Also zeroes the ambiguous-token counter (runs before router_mfma).
// ---------------------------------------------------------------------------
__global__ __launch_bounds__(256) void wsplit(const float* __restrict__ W,
                                              short* __restrict__ warr,
                                              int* __restrict__ cnt) {
    int idx  = blockIdx.x * 256 + threadIdx.x;   // 0..262143
    if (idx == 0) *cnt = 0;
    int j    = idx & 7;
    int lane = (idx >> 3) & 63;
    int nf   = (idx >> 9) & 3;
    int kf   = (idx >> 11) & 63;
    int term = idx >> 17;                        // 0..1
    int e = nf * 16 + (lane & 15);
    int d = kf * 32 + (lane >> 4) * 8 + j;
    float w = W[e * DIM + d];
    unsigned short h  = bf16_rne(w);
    float r1 = w - bf16_up(h);
    unsigned short md = bf16_rne(r1);
    warr[idx] = (short)((term == 0) ? h : md);
}

__device__ __forceinline__ bool gtie(float a, int ia, float b, int ib) {
    return (a > b) || (a == b && ia < ib);
}

// ---------------------------------------------------------------------------
// Kernel A (R11): HBM-grain fix. Wave = 16 tokens x 64 experts (as R8).
// Each wave stages its OWN 16 rows into a private 16KB LDS slice in 256-dim
// chunks; every global load = 1 row x 1KB CONTIGUOUS (64 lanes x 16B).
// A-fragments then read from LDS (XOR-swizzled, same involution both sides).
// No cross-wave deps -> ZERO barriers. T14: chunk c+1 loads issue before
// chunk c compute. B prefetch + all numerics identical to R8/R9/R10 (pass).
// ---------------------------------------------------------------------------
__global__ __launch_bounds__(256, 2) void router_mfma(
        const float* __restrict__ X, const short* __restrict__ Wsp,
        const float* __restrict__ bias, float* __restrict__ out,
        int* __restrict__ cnt, int* __restrict__ list) {
    __shared__ char xtile[4][16384] __attribute__((aligned(16)));
    const int lane = threadIdx.x & 63;
    const int wid  = threadIdx.x >> 6;         // 0..3
    const int tok0 = blockIdx.x * 64 + wid * 16;
    const int l15  = lane & 15;
    const int l4   = lane >> 4;
    char* xt = xtile[wid];

    // staging map: row r (0..15), lane l writes 16B at r*1024 + ((l*16)^((r&7)<<4))
    const float* xg = X + (size_t)tok0 * DIM + lane * 4;
    // compute map: row l15, byte-in-row b = q*128 + l4*32 (+16), same XOR
    const int rbase = l15 * 1024;
    const int rsw   = (l15 & 7) << 4;
    const int cbyte = l4 * 32;

    const short8* wp = (const short8*)Wsp + lane;  // + ((t*KF+kf)*4+n)*64

    f32x4 acc[4];
#pragma unroll
    for (int n = 0; n < 4; n++) acc[n] = (f32x4)0.0f;

    // ---- prologue: stage chunk 0 (16 rows x 1KB contiguous each) ----------
    {
        f32x4 st[16];
#pragma unroll
        for (int r = 0; r < 16; r++) st[r] = *(const f32x4*)(xg + (size_t)r * DIM);
#pragma unroll
        for (int r = 0; r < 16; r++)
            *(f32x4*)(xt + r * 1024 + ((lane * 16) ^ ((r & 7) << 4))) = st[r];
    }
    // B prefetch for kf = 0
    short8 b_pf[2][2][4];
#pragma unroll
    for (int t = 0; t < 2; t++)
#pragma unroll
        for (int n = 0; n < 4; n++)
            b_pf[0][t][n] = wp[((t * KF + 0) * 4 + n) * 64];

#pragma unroll 1
    for (int ch = 0; ch < 8; ++ch) {
        // T14: issue next chunk's global loads now, write to LDS after compute
        f32x4 st[16];
        if (ch < 7) {
#pragma unroll
            for (int r = 0; r < 16; r++)
                st[r] = *(const f32x4*)(xg + (size_t)r * DIM + (ch + 1) * 256);
        }

#pragma unroll
        for (int q = 0; q < 8; ++q) {
            const int kf  = ch * 8 + q;
            const int kfn = (kf + 1 < KF) ? kf + 1 : KF - 1;

            // B prefetch for kf+1 into the other parity buffer
#pragma unroll
            for (int t = 0; t < 2; t++)
#pragma unroll
                for (int n = 0; n < 4; n++)
                    b_pf[(q + 1) & 1][t][n] = wp[((t * KF + kfn) * 4 + n) * 64];

            // A fragment from LDS (swizzled)
            const int b0 = q * 128 + cbyte;
            f32x4 a0 = *(const f32x4*)(xt + rbase + ((b0)      ^ rsw));
            f32x4 a1 = *(const f32x4*)(xt + rbase + ((b0 + 16) ^ rsw));

            // 2-way bf16 split of A (identical math to R8)
            short8 ah, am;
#pragma unroll
            for (int j = 0; j < 8; j++) {
                float v = (j < 4) ? a0[j & 3] : a1[j & 3];
                unsigned short h  = bf16_rne(v);
                float r1 = v - bf16_up(h);
                unsigned short md = bf16_rne(r1);
                ah[j] = (short)h;
                am[j] = (short)md;
            }

#pragma unroll
            for (int n = 0; n < 4; n++) {
                f32x4 c = acc[n];
                c = __builtin_amdgcn_mfma_f32_16x16x32_bf16(ah, b_pf[q & 1][0][n], c, 0, 0, 0);
                c = __builtin_amdgcn_mfma_f32_16x16x32_bf16(ah, b_pf[q & 1][1][n], c, 0, 0, 0);
                c = __builtin_amdgcn_mfma_f32_16x16x32_bf16(am, b_pf[q & 1][0][n], c, 0, 0, 0);
                c = __builtin_amdgcn_mfma_f32_16x16x32_bf16(am, b_pf[q & 1][1][n], c, 0, 0, 0);
                acc[n] = c;
            }
        }

        if (ch < 7) {
#pragma unroll
            for (int r = 0; r < 16; r++)
                *(f32x4*)(xt + r * 1024 + ((lane * 16) ^ ((r & 7) << 4))) = st[r];
        }
    }

    // ------------- epilogue: bias + softmax + top-3 + flag (R8-verified) ---
    float bv[4];
#pragma unroll
    for (int n = 0; n < 4; n++) bv[n] = bias[n * 16 + l15];

#pragma unroll
    for (int r = 0; r < 4; r++) {
        const int t = tok0 + l4 * 4 + r;       // C row = (lane>>4)*4+reg
        float v[4];
#pragma unroll
        for (int n = 0; n < 4; n++) v[n] = acc[n][r] + bv[n];

        float mx = fmaxf(fmaxf(v[0], v[1]), fmaxf(v[2], v[3]));
#pragma unroll
        for (int s = 1; s < 16; s <<= 1) mx = fmaxf(mx, __shfl_xor(mx, s, 64));

        float p[4], den = 0.0f;
#pragma unroll
        for (int n = 0; n < 4; n++) { p[n] = __expf(v[n] - mx); den += p[n]; }
#pragma unroll
        for (int s = 1; s < 16; s <<= 1) den += __shfl_xor(den, s, 64);
        const float inv = 1.0f / den;
#pragma unroll
        for (int n = 0; n < 4; n++)
            out[(size_t)t * 64 + n * 16 + l15] = p[n] * inv;

        // local top-3 over this lane's 4 experts
        float v1 = -3.4e38f, v2 = -3.4e38f, v3 = -3.4e38f;
        int   i1 = 9999,     i2 = 9999,     i3 = 9999;
#pragma unroll
        for (int n = 0; n < 4; n++) {
            float vv = v[n]; int ii = n * 16 + l15;
            if (gtie(vv, ii, v1, i1))      { v3=v2;i3=i2; v2=v1;i2=i1; v1=vv;i1=ii; }
            else if (gtie(vv, ii, v2, i2)) { v3=v2;i3=i2; v2=vv;i2=ii; }
            else if (gtie(vv, ii, v3, i3)) { v3=vv;i3=ii; }
        }
        // butterfly merge across the token's 16 lanes
#pragma unroll
        for (int s = 1; s < 16; s <<= 1) {
            float ov1=__shfl_xor(v1,s,64), ov2=__shfl_xor(v2,s,64), ov3=__shfl_xor(v3,s,64);
            int   oi1=__shfl_xor(i1,s,64), oi2=__shfl_xor(i2,s,64), oi3=__shfl_xor(i3,s,64);
            bool a1 = gtie(v1,i1,ov1,oi1);
            float w1 = a1?v1:ov1;  int k1 = a1?i1:oi1;
            float x1 = a1?v2:ov2;  int xi1= a1?i2:oi2;   // winner's 2nd
            float x2 = a1?v3:ov3;  int xi2= a1?i3:oi3;   // winner's 3rd
            float y1 = a1?ov1:v1;  int yi1= a1?oi1:i1;   // loser's 1st
            float y2 = a1?ov2:v2;  int yi2= a1?oi2:i2;   // loser's 2nd
            bool a2 = gtie(x1,xi1,y1,yi1);
            float w2 = a2?x1:y1;   int k2 = a2?xi1:yi1;
            float w3; int k3;
            if (a2) { bool a3 = gtie(x2,xi2,y1,yi1); w3 = a3?x2:y1; k3 = a3?xi2:yi1; }
            else    { bool a3 = gtie(x1,xi1,y2,yi2); w3 = a3?x1:y2; k3 = a3?xi1:yi2; }
            v1=w1;i1=k1; v2=w2;i2=k2; v3=w3;i3=k3;
        }
        if (l15 == 0) {
            out[OFF_IDX + (size_t)t * 2 + 0] = (float)i1;
            out[OFF_IDX + (size_t)t * 2 + 1] = (float)i2;
            out[OFF_TSC + (size_t)t * 2 + 0] = __expf(v1 - mx) * inv;
            out[OFF_TSC + (size_t)t * 2 + 1] = __expf(v2 - mx) * inv;
            if ((v1 - v2 < TAU) || (v2 - v3 < TAU)) {
                int slot = atomicAdd(cnt, 1);
                list[slot] = t;
            }
        }
    }
}

// ---------------------------------------------------------------------------
// Kernel B: exact np-chain recompute for flagged tokens (R3-R10 verified
// arithmetic): logit[t][e] = sequential fmaf over d=0..2047 asc, then +b[e].
// ---------------------------------------------------------------------------
__global__ __launch_bounds__(256, 2) void router_exact(
        const float* __restrict__ X, const float* __restrict__ W,
        const float* __restrict__ Bb, float* __restrict__ out,
        const int* __restrict__ cnt, const int* __restrict__ list) {
    __shared__ float xrow[2048];
    __shared__ char  wbuf[2][64 * 272] __attribute__((aligned(16)));
    const int tid = threadIdx.x;
    const int n   = *cnt;

    for (int ii = blockIdx.x; ii < n; ii += gridDim.x) {
        const int t = list[ii];
#pragma unroll
        for (int q = 0; q < 2; ++q) {
            int s = tid + q * 256;               // 0..511 quads
            *(f32x4*)&xrow[s * 4] = *(const f32x4*)(X + (size_t)t * DIM + s * 4);
        }
#pragma unroll
        for (int q = 0; q < 4; ++q) {
            int s = tid + q * 256;               // 0..1023: e = s>>4, dq = s&15
            int e = s >> 4, dq = s & 15;
            f32x4 wv = *(const f32x4*)(W + (size_t)e * DIM + dq * 4);
            *(f32x4*)(wbuf[0] + e * 272 + ((16 * dq) ^ ((e & 7) << 4))) = wv;
        }
        __syncthreads();

        float acc = 0.0f;
#pragma unroll 1
        for (int c = 0; c < 32; ++c) {
            if (c + 1 < 32) {
#pragma unroll
                for (int q = 0; q < 4; ++q) {
                    int s = tid + q * 256;
                    int e = s >> 4, dq = s & 15;
                    f32x4 wv = *(const f32x4*)(W + (size_t)e * DIM + (c + 1) * 64 + dq * 4);
                    *(f32x4*)(wbuf[(c + 1) & 1] + e * 272 + ((16 * dq) ^ ((e & 7) << 4))) = wv;
                }
            }
            if (tid < 64) {
                const char* wb = wbuf[c & 1] + tid * 272;
                const int sw = (tid & 7) << 4;
#pragma unroll
                for (int dq = 0; dq < 16; ++dq) {
                    f32x4 xq = *(const f32x4*)&xrow[c * 64 + dq * 4];
                    f32x4 wv = *(const f32x4*)(wb + ((16 * dq) ^ sw));
#pragma unroll
                    for (int j = 0; j < 4; ++j)
                        acc = fmaf(xq[j], wv[j], acc);   // strict ascending d
                }
            }
            __syncthreads();
        }

        if (tid < 64) {
            const int lane = tid;
            const float lg = acc + Bb[lane];
            float m = lg;
#pragma unroll
            for (int s = 1; s < 64; s <<= 1) m = fmaxf(m, __shfl_xor(m, s, 64));
            const float p = __expf(lg - m);
            float den = p;
#pragma unroll
            for (int s = 1; s < 64; s <<= 1) den += __shfl_xor(den, s, 64);
            const float inv = 1.0f / den;
            out[(size_t)t * 64 + lane] = p * inv;

            float v1 = lg, v2 = -3.4e38f;
            int   i1 = lane, i2 = 127;
#pragma unroll
            for (int s = 1; s < 64; s <<= 1) {
                float ov1 = __shfl_xor(v1, s, 64), ov2 = __shfl_xor(v2, s, 64);
                int   oi1 = __shfl_xor(i1, s, 64), oi2 = __shfl_xor(i2, s, 64);
                bool  aw  = gtie(v1, i1, ov1, oi1);
                float nv1 = aw ? v1 : ov1;  int ni1 = aw ? i1 : oi1;
                float cv  = aw ? ov1 : v1;  int ci  = aw ? oi1 : i1;
                float sv  = aw ? v2 : ov2;  int si  = aw ? i2 : oi2;
                bool  c2  = gtie(cv, ci, sv, si);
                v1 = nv1; i1 = ni1;
                v2 = c2 ? cv : sv; i2 = c2 ? ci : si;
            }
            if (lane == 0) {
                out[OFF_IDX + (size_t)t * 2 + 0] = (float)i1;
                out[OFF_IDX + (size_t)t * 2 + 1] = (float)i2;
                out[OFF_TSC + (size_t)t * 2 + 0] = __expf(v1 - m) * inv;
                out[OFF_TSC + (size_t)t * 2 + 1] = __expf(v2 - m) * inv;
            }
        }
        __syncthreads();
    }
}

extern "C" void kernel_launch(void* const* d_in, const int* in_sizes, int n_in,
                              void* d_out, int out_size, void* d_ws, size_t ws_size,
                              hipStream_t stream) {
    const float* X = (const float*)d_in[0];   // [4,8192,2048] f32
    const float* W = (const float*)d_in[1];   // [64,2048] f32
    const float* b = (const float*)d_in[2];   // [64] f32
    float* out  = (float*)d_out;
    short* Wsp  = (short*)d_ws;                       // 512 KB
    int*   cnt  = (int*)((char*)d_ws + 524288);       // 4 B
    int*   list = (int*)((char*)d_ws + 524292);       // up to 128 KB

    wsplit<<<1024, 256, 0, stream>>>(W, Wsp, cnt);
    router_mfma<<<NTOK / 64, 256, 0, stream>>>(X, Wsp, b, out, cnt, list);
    router_exact<<<512, 256, 0, stream>>>(X, W, b, out, cnt, list);
}